// Round 1
// baseline (1834.380 us; speedup 1.0000x reference)
//
#include <hip/hip_runtime.h>
#include <hip/hip_bf16.h>

#define N_   100000
#define E_   3200000
#define IN_  128
#define H_   256
#define OUT_ 256
#define G_   64
#define EPSV 1e-5f

// ---------------- CSR build ----------------
__global__ void k_count(const int* __restrict__ dst, int* __restrict__ deg){
  int e = blockIdx.x*256 + threadIdx.x;
  if (e < E_) atomicAdd(&deg[dst[e]], 1);
}

__global__ __launch_bounds__(1024) void k_scan1(const int* __restrict__ deg, int* __restrict__ rowp,
                                                int* __restrict__ bsums){
  __shared__ int s[1024];
  int t = threadIdx.x;
  int i = blockIdx.x*1024 + t;
  int v = (i < N_) ? (deg[i] + 1) : 0;   // +1 = self loop
  s[t] = v;
  __syncthreads();
  for (int o = 1; o < 1024; o <<= 1){
    int x = (t >= o) ? s[t-o] : 0;
    __syncthreads();
    s[t] += x;
    __syncthreads();
  }
  if (i < N_) rowp[i+1] = s[t];
  if (t == 1023) bsums[blockIdx.x] = s[1023];
}

__global__ void k_scan2(int* __restrict__ bsums, int nb){
  __shared__ int s[128];
  int t = threadIdx.x;
  int v = (t < nb) ? bsums[t] : 0;
  s[t] = v;
  __syncthreads();
  for (int o = 1; o < 128; o <<= 1){
    int x = (t >= o) ? s[t-o] : 0;
    __syncthreads();
    s[t] += x;
    __syncthreads();
  }
  if (t < nb) bsums[t] = s[t] - v;       // exclusive
}

__global__ __launch_bounds__(1024) void k_scan3(const int* __restrict__ deg, int* __restrict__ rowp,
                                                const int* __restrict__ bsums, int* __restrict__ cursor){
  int t = threadIdx.x;
  int i = blockIdx.x*1024 + t;
  if (i < N_){
    int rp = rowp[i+1] + bsums[blockIdx.x];
    rowp[i+1] = rp;
    cursor[i] = rp - (deg[i] + 1);
  }
  if (i == 0) rowp[0] = 0;
}

__global__ void k_fill(const int* __restrict__ ei, int* __restrict__ cursor, int* __restrict__ col){
  int e = blockIdx.x*256 + threadIdx.x;
  if (e < E_){
    int d = ei[E_ + e];
    int pos = atomicAdd(&cursor[d], 1);
    col[pos] = ei[e];
  } else if (e < E_ + N_){
    int i = e - E_;
    int pos = atomicAdd(&cursor[i], 1);
    col[pos] = i;
  }
}

// ---------------- fp32 SGEMM: C[nrows,256] = A[nrows,K] @ W[K,256] ----------------
template<int K>
__global__ __launch_bounds__(256) void k_gemm(const float* __restrict__ A, const float* __restrict__ W,
                                              float* __restrict__ C, int nrows){
  __shared__ float As[16][68];   // transposed A tile: As[k][m], pad 68 to break conflicts
  __shared__ float Ws[16][68];   // Ws[k][n]
  const int t  = threadIdx.x;
  const int bm = blockIdx.x * 64;
  const int bn = blockIdx.y * 64;
  const int lm = t >> 2,  lk = (t & 3) * 4;    // A staging
  const int wk = t >> 4,  wn = (t & 15) * 4;   // W staging
  const int tm = (t >> 4) * 4, tn = (t & 15) * 4; // compute tile
  float acc[4][4];
  #pragma unroll
  for (int i=0;i<4;i++){
    #pragma unroll
    for (int j=0;j<4;j++) acc[i][j]=0.f;
  }
  for (int kb = 0; kb < K; kb += 16){
    const int arow = bm + lm;
    float4 av = make_float4(0.f,0.f,0.f,0.f);
    if (arow < nrows) av = *reinterpret_cast<const float4*>(A + (size_t)arow*K + kb + lk);
    const float4 wv = *reinterpret_cast<const float4*>(W + (size_t)(kb + wk)*256 + bn + wn);
    __syncthreads();
    As[lk+0][lm]=av.x; As[lk+1][lm]=av.y; As[lk+2][lm]=av.z; As[lk+3][lm]=av.w;
    *reinterpret_cast<float4*>(&Ws[wk][wn]) = wv;
    __syncthreads();
    #pragma unroll
    for (int k=0;k<16;k++){
      const float4 a  = *reinterpret_cast<const float4*>(&As[k][tm]);
      const float4 bv = *reinterpret_cast<const float4*>(&Ws[k][tn]);
      acc[0][0]+=a.x*bv.x; acc[0][1]+=a.x*bv.y; acc[0][2]+=a.x*bv.z; acc[0][3]+=a.x*bv.w;
      acc[1][0]+=a.y*bv.x; acc[1][1]+=a.y*bv.y; acc[1][2]+=a.y*bv.z; acc[1][3]+=a.y*bv.w;
      acc[2][0]+=a.z*bv.x; acc[2][1]+=a.z*bv.y; acc[2][2]+=a.z*bv.z; acc[2][3]+=a.z*bv.w;
      acc[3][0]+=a.w*bv.x; acc[3][1]+=a.w*bv.y; acc[3][2]+=a.w*bv.z; acc[3][3]+=a.w*bv.w;
    }
  }
  #pragma unroll
  for (int i=0;i<4;i++){
    const int row = bm + tm + i;
    if (row < nrows){
      float4 o = make_float4(acc[i][0],acc[i][1],acc[i][2],acc[i][3]);
      *reinterpret_cast<float4*>(C + (size_t)row*256 + bn + tn) = o;
    }
  }
}

// ---------------- attention score dots: s_src[i]=h[i]·a_src, s_dst[i]=h[i]·a_dst ----------------
__global__ __launch_bounds__(256) void k_sdots(const float* __restrict__ h, const float* __restrict__ a_s,
                                               const float* __restrict__ a_d, float* __restrict__ ssrc,
                                               float* __restrict__ sdst){
  const int lane = threadIdx.x & 63;
  const int node = blockIdx.x*4 + (threadIdx.x >> 6);
  if (node >= N_) return;
  const float4 hv = *reinterpret_cast<const float4*>(h + (size_t)node*256 + lane*4);
  const float4 as = *reinterpret_cast<const float4*>(a_s + lane*4);
  const float4 ad = *reinterpret_cast<const float4*>(a_d + lane*4);
  float ps = hv.x*as.x + hv.y*as.y + hv.z*as.z + hv.w*as.w;
  float pd = hv.x*ad.x + hv.y*ad.y + hv.z*ad.z + hv.w*ad.w;
  for (int o = 32; o; o >>= 1){
    ps += __shfl_xor(ps, o, 64);
    pd += __shfl_xor(pd, o, 64);
  }
  if (lane == 0){ ssrc[node] = ps; sdst[node] = pd; }
}

// ---------------- GAT aggregation: one wave per destination node ----------------
// out_i = (sum_j exp(e_ij) * h_j) / (sum_j exp(e_ij)) + b     (max-shift-free softmax, exactly
// equivalent to the reference's segment_max form; |e| <~ 10 so exp is fp32-safe)
__global__ __launch_bounds__(256) void k_agg(const float* __restrict__ h, const int* __restrict__ col,
                                             const int* __restrict__ rowp, const float* __restrict__ ssrc,
                                             const float* __restrict__ sdst, const float* __restrict__ bias,
                                             float* __restrict__ out){
  const int lane = threadIdx.x & 63;
  const int node = blockIdx.x*4 + (threadIdx.x >> 6);
  if (node >= N_) return;
  int p = rowp[node];
  const int end = rowp[node+1];
  const float sd = sdst[node];
  float den = 0.f;
  float ax0=0.f,ay0=0.f,az0=0.f,aw0=0.f, ax1=0.f,ay1=0.f,az1=0.f,aw1=0.f;
  for (; p + 2 <= end; p += 2){
    const int s0 = col[p], s1 = col[p+1];
    float e0 = ssrc[s0] + sd; e0 = e0 > 0.f ? e0 : 0.2f*e0;
    float e1 = ssrc[s1] + sd; e1 = e1 > 0.f ? e1 : 0.2f*e1;
    const float w0 = expf(e0), w1 = expf(e1);
    const float4 h0 = *reinterpret_cast<const float4*>(h + (size_t)s0*256 + lane*4);
    const float4 h1 = *reinterpret_cast<const float4*>(h + (size_t)s1*256 + lane*4);
    den += w0 + w1;
    ax0 += w0*h0.x; ay0 += w0*h0.y; az0 += w0*h0.z; aw0 += w0*h0.w;
    ax1 += w1*h1.x; ay1 += w1*h1.y; az1 += w1*h1.z; aw1 += w1*h1.w;
  }
  if (p < end){
    const int s0 = col[p];
    float e0 = ssrc[s0] + sd; e0 = e0 > 0.f ? e0 : 0.2f*e0;
    const float w0 = expf(e0);
    const float4 h0 = *reinterpret_cast<const float4*>(h + (size_t)s0*256 + lane*4);
    den += w0;
    ax0 += w0*h0.x; ay0 += w0*h0.y; az0 += w0*h0.z; aw0 += w0*h0.w;
  }
  const float inv = 1.f/den;
  const float4 bb = *reinterpret_cast<const float4*>(bias + lane*4);
  float4 r;
  r.x = (ax0+ax1)*inv + bb.x;
  r.y = (ay0+ay1)*inv + bb.y;
  r.z = (az0+az1)*inv + bb.z;
  r.w = (aw0+aw1)*inv + bb.w;
  *reinterpret_cast<float4*>(out + (size_t)node*256 + lane*4) = r;
}

// ---------------- batch norm ----------------
__global__ __launch_bounds__(256) void k_bnstats(const float* __restrict__ x, float* __restrict__ bsum,
                                                 float* __restrict__ bsq){
  const int f = threadIdx.x;
  float s = 0.f, q = 0.f;
  for (int r = blockIdx.x; r < N_; r += gridDim.x){
    const float v = x[(size_t)r*256 + f];
    s += v; q += v*v;
  }
  atomicAdd(&bsum[f], s);
  atomicAdd(&bsq[f], q);
}

__global__ void k_bnprep(const float* __restrict__ g, const float* __restrict__ be,
                         float* __restrict__ bsum, float* __restrict__ bsq){
  const int f = threadIdx.x;
  const float mean = bsum[f] * (1.0f/N_);
  const float var  = bsq[f]  * (1.0f/N_) - mean*mean;
  const float sc = g[f] / sqrtf(var + EPSV);
  bsum[f] = sc;
  bsq[f]  = be[f] - mean*sc;
}

__global__ __launch_bounds__(256) void k_bnapply(float* __restrict__ x, const float* __restrict__ sc,
                                                 const float* __restrict__ sh){
  const long long total = (long long)N_ * 64;   // float4 count
  for (long long i = (long long)blockIdx.x*256 + threadIdx.x; i < total; i += (long long)gridDim.x*256){
    const int f4 = ((int)(i & 63)) * 4;
    float4 v = *reinterpret_cast<const float4*>(x + i*4);
    const float4 s = *reinterpret_cast<const float4*>(sc + f4);
    const float4 t = *reinterpret_cast<const float4*>(sh + f4);
    v.x = fmaxf(v.x*s.x + t.x, 0.f);
    v.y = fmaxf(v.y*s.y + t.y, 0.f);
    v.z = fmaxf(v.z*s.z + t.z, 0.f);
    v.w = fmaxf(v.w*s.w + t.w, 0.f);
    *reinterpret_cast<float4*>(x + i*4) = v;
  }
}

// ---------------- global mean pool (batch is sorted -> run-length partials) ----------------
__global__ __launch_bounds__(256) void k_pool(const float* __restrict__ x, const int* __restrict__ batch,
                                              float* __restrict__ psum, float* __restrict__ pcnt){
  const int f = threadIdx.x;
  const int RPB = (N_ + gridDim.x - 1) / gridDim.x;
  const int r0 = blockIdx.x * RPB;
  const int r1 = min(r0 + RPB, N_);
  if (r0 >= N_) return;
  float local = 0.f, c = 0.f;
  int curg = -1;
  for (int r = r0; r < r1; ++r){
    const int g = batch[r];
    if (g != curg){
      if (curg >= 0){
        atomicAdd(&psum[curg*256 + f], local);
        if (f == 0) atomicAdd(&pcnt[curg], c);
      }
      curg = g; local = 0.f; c = 0.f;
    }
    local += x[(size_t)r*256 + f];
    c += 1.f;
  }
  if (curg >= 0){
    atomicAdd(&psum[curg*256 + f], local);
    if (f == 0) atomicAdd(&pcnt[curg], c);
  }
}

// ---------------- FC head ----------------
__global__ __launch_bounds__(256) void k_fc1(const float* __restrict__ psum, const float* __restrict__ pcnt,
                                             const float* __restrict__ w, const float* __restrict__ b,
                                             float* __restrict__ z){
  __shared__ float p[256];
  const int g = blockIdx.x, f = threadIdx.x;
  const float cnt = fmaxf(pcnt[g], 1.f);
  p[f] = psum[g*256 + f] / cnt;
  __syncthreads();
  float acc = b[f];
  #pragma unroll 8
  for (int k = 0; k < 256; ++k) acc += p[k] * w[k*256 + f];
  z[g*256 + f] = fmaxf(acc, 0.f);
}

__global__ __launch_bounds__(128) void k_fc2(const float* __restrict__ zin, const float* __restrict__ w,
                                             const float* __restrict__ b, float* __restrict__ z){
  __shared__ float p[256];
  const int g = blockIdx.x, f = threadIdx.x;
  p[f] = zin[g*256 + f];
  p[f+128] = zin[g*256 + f + 128];
  __syncthreads();
  float acc = b[f];
  #pragma unroll 8
  for (int k = 0; k < 256; ++k) acc += p[k] * w[k*128 + f];
  z[g*128 + f] = fmaxf(acc, 0.f);
}

__global__ __launch_bounds__(64) void k_fc3(const float* __restrict__ zin, const float* __restrict__ w,
                                            const float* __restrict__ b, float* __restrict__ out){
  const int g = threadIdx.x;   // 64 graphs
  float acc = b[0];
  #pragma unroll 8
  for (int k = 0; k < 128; ++k) acc += zin[g*128 + k] * w[k];
  out[g] = acc;
}

// ---------------- launch ----------------
extern "C" void kernel_launch(void* const* d_in, const int* in_sizes, int n_in,
                              void* d_out, int out_size, void* d_ws, size_t ws_size,
                              hipStream_t stream){
  (void)in_sizes; (void)n_in; (void)out_size; (void)ws_size;
  const float* x    = (const float*)d_in[0];
  const float* W1   = (const float*)d_in[1];
  const float* a_s1 = (const float*)d_in[2];
  const float* a_d1 = (const float*)d_in[3];
  const float* b1   = (const float*)d_in[4];
  const float* g1   = (const float*)d_in[5];
  const float* be1  = (const float*)d_in[6];
  const float* W2   = (const float*)d_in[7];
  const float* a_s2 = (const float*)d_in[8];
  const float* a_d2 = (const float*)d_in[9];
  const float* b2   = (const float*)d_in[10];
  const float* g2   = (const float*)d_in[11];
  const float* be2  = (const float*)d_in[12];
  const float* fc1w = (const float*)d_in[13];
  const float* fc1b = (const float*)d_in[14];
  const float* fc2w = (const float*)d_in[15];
  const float* fc2b = (const float*)d_in[16];
  const float* fc3w = (const float*)d_in[17];
  const float* fc3b = (const float*)d_in[18];
  const int*   ei   = (const int*)d_in[19];
  const int*   batch= (const int*)d_in[20];
  float* out = (float*)d_out;

  char* ws = (char*)d_ws;
  size_t off = 0;
  auto alloc = [&](size_t bytes)->char*{
    char* p = ws + off;
    off += (bytes + 255) & ~(size_t)255;
    return p;
  };
  float* h      = (float*)alloc((size_t)N_*256*4);
  float* agg    = (float*)alloc((size_t)N_*256*4);
  int*   col    = (int*)  alloc((size_t)(E_+N_)*4);
  int*   rowp   = (int*)  alloc((size_t)(N_+1)*4);
  int*   deg    = (int*)  alloc((size_t)N_*4);
  int*   cursor = (int*)  alloc((size_t)N_*4);
  float* ssrc   = (float*)alloc((size_t)N_*4);
  float* sdst   = (float*)alloc((size_t)N_*4);
  float* bns    = (float*)alloc(512*4);            // sum[256] | sumsq[256] -> scale | shift
  float* pooled = (float*)alloc((G_*256 + G_)*4);  // sums | counts
  float* z1     = (float*)alloc(G_*256*4);
  float* z2     = (float*)alloc(G_*128*4);
  int*   bsums  = (int*)  alloc(1024*4);

  const int NCHUNK = (N_ + 1023) / 1024;   // 98

  // ---- CSR by dst (with self loops) ----
  hipMemsetAsync(deg, 0, (size_t)N_*4, stream);
  k_count<<<(E_+255)/256, 256, 0, stream>>>(ei + E_, deg);
  k_scan1<<<NCHUNK, 1024, 0, stream>>>(deg, rowp, bsums);
  k_scan2<<<1, 128, 0, stream>>>(bsums, NCHUNK);
  k_scan3<<<NCHUNK, 1024, 0, stream>>>(deg, rowp, bsums, cursor);
  k_fill<<<(E_+N_+255)/256, 256, 0, stream>>>(ei, cursor, col);

  // ---- layer 1 ----
  k_gemm<IN_><<<dim3((N_+63)/64, 4), 256, 0, stream>>>(x, W1, h, N_);
  k_sdots<<<(N_+3)/4, 256, 0, stream>>>(h, a_s1, a_d1, ssrc, sdst);
  k_agg<<<(N_+3)/4, 256, 0, stream>>>(h, col, rowp, ssrc, sdst, b1, agg);
  hipMemsetAsync(bns, 0, 512*4, stream);
  k_bnstats<<<512, 256, 0, stream>>>(agg, bns, bns + 256);
  k_bnprep<<<1, 256, 0, stream>>>(g1, be1, bns, bns + 256);
  k_bnapply<<<2048, 256, 0, stream>>>(agg, bns, bns + 256);

  // ---- layer 2 (h buffer reused for h2) ----
  k_gemm<H_><<<dim3((N_+63)/64, 4), 256, 0, stream>>>(agg, W2, h, N_);
  k_sdots<<<(N_+3)/4, 256, 0, stream>>>(h, a_s2, a_d2, ssrc, sdst);
  k_agg<<<(N_+3)/4, 256, 0, stream>>>(h, col, rowp, ssrc, sdst, b2, agg);
  hipMemsetAsync(bns, 0, 512*4, stream);
  k_bnstats<<<512, 256, 0, stream>>>(agg, bns, bns + 256);
  k_bnprep<<<1, 256, 0, stream>>>(g2, be2, bns, bns + 256);
  k_bnapply<<<2048, 256, 0, stream>>>(agg, bns, bns + 256);

  // ---- pool + head ----
  hipMemsetAsync(pooled, 0, (size_t)(G_*256 + G_)*4, stream);
  k_pool<<<512, 256, 0, stream>>>(agg, batch, pooled, pooled + G_*256);
  k_fc1<<<G_, 256, 0, stream>>>(pooled, pooled + G_*256, fc1w, fc1b, z1);
  k_fc2<<<G_, 128, 0, stream>>>(z1, fc2w, fc2b, z2);
  k_fc3<<<1, 64, 0, stream>>>(z2, fc3w, fc3b, out);
}